// Round 5
// baseline (6400.482 us; speedup 1.0000x reference)
//
#include <hip/hip_runtime.h>
#include <hip/hip_bf16.h>

#define DEV __device__ __forceinline__

typedef __attribute__((ext_vector_type(8))) short short8;
typedef __attribute__((ext_vector_type(4))) float f32x4;
typedef __attribute__((ext_vector_type(4))) unsigned int u32x4;

static constexpr int B_ = 16, S_ = 1024, H_ = 1024, NS_ = 32, HEADS_ = 16, L_ = 5;
static constexpr int G4H = 4096;
static constexpr int LSTM_GRID = 64;

DEV unsigned short f2bf(float f){
  union { float f; unsigned int i; } u; u.f = f;
  unsigned int r = (u.i + 0x7fffu + ((u.i >> 16) & 1u)) >> 16;
  return (unsigned short)r;
}
DEV float bf2f(unsigned short h){
  union { unsigned int i; float f; } u; u.i = ((unsigned int)h) << 16;
  return u.f;
}
DEV float sigm(float x){ return 1.f / (1.f + __expf(-x)); }
DEV float tanh_(float x){
  x = fminf(30.f, fmaxf(-30.f, x));
  float e = __expf(-2.f * x);
  return (1.f - e) / (1.f + e);
}

// coherent (LLC-level) 16B load/store: bypass L1+L2 so cross-XCD exchange needs NO cache fences
DEV short8 load_coh16(const void* p){
  short8 r;
  asm volatile("global_load_dwordx4 %0, %1, off sc0 sc1" : "=v"(r) : "v"(p));
  return r;
}
DEV void store_coh16(void* p, u32x4 v){
  asm volatile("global_store_dwordx4 %0, %1, off sc0 sc1" :: "v"(p), "v"(v) : "memory");
}

// ---------------- span_of map: span_of[b][t] = span index or -1 ----------------
__global__ void k_spanof(const int* __restrict__ head, const int* __restrict__ tail,
                         int* __restrict__ spanof){
  const int b = blockIdx.x;
  for (int t = threadIdx.x; t < S_; t += blockDim.x) spanof[b * S_ + t] = -1;
  __syncthreads();
  if (threadIdx.x < NS_){
    const int n = threadIdx.x;
    const int h = head[b * NS_ + n], tl = tail[b * NS_ + n];
    for (int t = h + 1; t < tl; ++t) spanof[b * S_ + t] = n;
  }
}

// ---------------- gates_x GEMM -> gx in per-LSTM-block layout ----------------
// gx ushort4 index: ((t*64 + cu)*64 + (w*16 + n))*4 + bg   (contiguous 2KB per block per step)
__global__ __launch_bounds__(256) void k_gates(const float* __restrict__ enc,
    const float* __restrict__ Wih, const float* __restrict__ bih,
    const float* __restrict__ bhh, unsigned short* __restrict__ gx){
  const int nb = blockIdx.x;   // 0..31  (N=4096 / 128)
  const int mb = blockIdx.y;   // 0..127 (M=16384 / 128); m = t*16 + b
  __shared__ __align__(16) unsigned short As[128 * 40];
  __shared__ __align__(16) unsigned short Bs[128 * 40];
  const int tid = threadIdx.x, w = tid >> 6, l = tid & 63;
  const int wm = (w >> 1) * 64, wn = (w & 1) * 64;
  const int cl = l & 15, bg = l >> 4;
  f32x4 acc[4][4] = {};
  const int t0 = mb * 8, n0 = nb * 128;
  const int srow = tid >> 1, skq = (tid & 1) * 16;
  const int sb = srow & 15, stt = t0 + (srow >> 4);
  const float* Asrc = enc + ((size_t)sb * S_ + stt) * H_ + skq;
  const float* Bsrc = Wih + (size_t)(n0 + srow) * H_ + skq;
  for (int k0 = 0; k0 < H_; k0 += 32){
    #pragma unroll
    for (int q = 0; q < 4; ++q){
      float4 a = *(const float4*)(Asrc + k0 + q * 4);
      float4 b = *(const float4*)(Bsrc + k0 + q * 4);
      ushort4 ua; ua.x = f2bf(a.x); ua.y = f2bf(a.y); ua.z = f2bf(a.z); ua.w = f2bf(a.w);
      ushort4 ub; ub.x = f2bf(b.x); ub.y = f2bf(b.y); ub.z = f2bf(b.z); ub.w = f2bf(b.w);
      *(ushort4*)(As + srow * 40 + skq + q * 4) = ua;
      *(ushort4*)(Bs + srow * 40 + skq + q * 4) = ub;
    }
    __syncthreads();
    short8 af[4], bf[4];
    const int kq = bg * 8;
    #pragma unroll
    for (int i = 0; i < 4; ++i) af[i] = *(const short8*)(As + (wm + i * 16 + cl) * 40 + kq);
    #pragma unroll
    for (int i = 0; i < 4; ++i) bf[i] = *(const short8*)(Bs + (wn + i * 16 + cl) * 40 + kq);
    #pragma unroll
    for (int mi = 0; mi < 4; ++mi)
      #pragma unroll
      for (int ni = 0; ni < 4; ++ni)
        acc[mi][ni] = __builtin_amdgcn_mfma_f32_16x16x32_bf16(af[mi], bf[ni], acc[mi][ni], 0, 0, 0);
    __syncthreads();
  }
  #pragma unroll
  for (int ni = 0; ni < 4; ++ni){
    const int c = n0 + wn + ni * 16 + cl;
    const float bias = bih[c] + bhh[c];
    const int g = c >> 10, j = c & 1023;
    const int cuq = j >> 4, wq = (j >> 2) & 3, jjq = j & 3;
    const int nq = jjq * 4 + g;
    #pragma unroll
    for (int mi = 0; mi < 4; ++mi){
      const int tg = t0 + ((wm + mi * 16) >> 4);
      ushort4 o;
      o.x = f2bf(acc[mi][ni].x + bias);
      o.y = f2bf(acc[mi][ni].y + bias);
      o.z = f2bf(acc[mi][ni].z + bias);
      o.w = f2bf(acc[mi][ni].w + bias);
      const size_t u4i = (((size_t)tg * 64 + cuq) * 64 + (wq * 16 + nq)) * 4 + bg;
      *((ushort4*)gx + u4i) = o;
    }
  }
}

// ---------------- persistent LSTM + fused span pooling ----------------
// 64 blocks x 256 thr, 1 block/CU. W_hh fragments in VGPRs (128/lane), h fragments
// loaded coherent->VGPRs each step. Distributed tag-flag barrier (no central atomic).
// hbuf layout: [parity][b][j] plain bf16. tags: [parity][64] uint, 64B stride.
__global__ __launch_bounds__(256, 1) void k_lstm(const float* __restrict__ Whh,
    const unsigned short* __restrict__ gx, const int* __restrict__ spanof,
    unsigned short* __restrict__ hbuf, unsigned int* __restrict__ tags,
    float* __restrict__ sums){
  __shared__ __align__(16) unsigned short Hs[256];   // [b][jl] 16x16 staging
  const int cu = blockIdx.x, tid = threadIdx.x;
  const int w = tid >> 6, l = tid & 63;
  const int n = l & 15, bg = l >> 4;
  const int g = n & 3, jj = n >> 2;
  const int j = cu * 16 + w * 4 + jj;    // my h column
  const int bstar = bg * 4 + g;          // my owned batch (C-row mapping)
  const int jl = w * 4 + jj;             // local h column

  // ---- stage my W_hh B-fragments: col = g*H + j, k = kk*32 + bg*8 + [0..8) ----
  short8 wr[32];
  {
    const float* ws = Whh + (size_t)(g * H_ + j) * H_ + bg * 8;
    #pragma unroll
    for (int kk = 0; kk < 32; ++kk){
      float4 x = *(const float4*)(ws + kk * 32);
      float4 y = *(const float4*)(ws + kk * 32 + 4);
      short8 v;
      v[0] = (short)f2bf(x.x); v[1] = (short)f2bf(x.y);
      v[2] = (short)f2bf(x.z); v[3] = (short)f2bf(x.w);
      v[4] = (short)f2bf(y.x); v[5] = (short)f2bf(y.y);
      v[6] = (short)f2bf(y.z); v[7] = (short)f2bf(y.w);
      wr[kk] = v;
    }
  }

  const ushort4* gxp = (const ushort4*)gx + ((size_t)cu * 64 + w * 16 + n) * 4 + bg;
  const int* sp = spanof + (size_t)bstar * S_;

  float cstate = 0.f, pool = 0.f;
  int curspan = -1;

  for (int t = 0; t < S_; ++t){
    const int p = t & 1;
    const ushort4 gxv = gxp[(size_t)t * 16384];     // issue early (LLC-resident)
    const int s = sp[t];
    { // poll distributed tags: lane l watches block l
      const unsigned int* tp = tags + (size_t)p * 1024 + (size_t)l * 16;
      unsigned int v = __hip_atomic_load(tp, __ATOMIC_RELAXED, __HIP_MEMORY_SCOPE_AGENT);
      int guard = 0;
      while (!__all(v == (unsigned int)t)){
        __builtin_amdgcn_s_sleep(1);
        v = __hip_atomic_load(tp, __ATOMIC_RELAXED, __HIP_MEMORY_SCOPE_AGENT);
        if (++guard > 2000000) break;
      }
    }
    // coherent h A-fragment loads: row n, k-chunk kk*64 + bg*16 bytes
    short8 hv[32];
    {
      const unsigned char* hb = (const unsigned char*)hbuf + p * 32768 + n * 2048 + bg * 16;
      #pragma unroll
      for (int kk = 0; kk < 32; ++kk) hv[kk] = load_coh16(hb + kk * 64);
      asm volatile("s_waitcnt vmcnt(0)" ::: "memory");
      __builtin_amdgcn_sched_barrier(0);
    }
    f32x4 a0 = {0,0,0,0}, a1 = {0,0,0,0}, a2 = {0,0,0,0}, a3 = {0,0,0,0};
    #pragma unroll
    for (int kk = 0; kk < 32; kk += 4){
      a0 = __builtin_amdgcn_mfma_f32_16x16x32_bf16(hv[kk + 0], wr[kk + 0], a0, 0, 0, 0);
      a1 = __builtin_amdgcn_mfma_f32_16x16x32_bf16(hv[kk + 1], wr[kk + 1], a1, 0, 0, 0);
      a2 = __builtin_amdgcn_mfma_f32_16x16x32_bf16(hv[kk + 2], wr[kk + 2], a2, 0, 0, 0);
      a3 = __builtin_amdgcn_mfma_f32_16x16x32_bf16(hv[kk + 3], wr[kk + 3], a3, 0, 0, 0);
    }
    f32x4 acc = (a0 + a1) + (a2 + a3);
    const float x0 = acc.x + bf2f(gxv.x);
    const float x1 = acc.y + bf2f(gxv.y);
    const float x2 = acc.z + bf2f(gxv.z);
    const float x3 = acc.w + bf2f(gxv.w);
    // 4-lane transpose: gather all 4 gate types for batch bstar
    const float s1 = (g==0)?x1:(g==1)?x0:(g==2)?x3:x2;   // beta = g^1
    const float s2 = (g==0)?x2:(g==1)?x3:(g==2)?x0:x1;   // beta = g^2
    const float s3 = (g==0)?x3:(g==1)?x2:(g==2)?x1:x0;   // beta = g^3
    const float r1 = __shfl_xor(s1, 1, 64);
    const float r2 = __shfl_xor(s2, 2, 64);
    const float r3 = __shfl_xor(s3, 3, 64);
    const float own = (g==0)?x0:(g==1)?x1:(g==2)?x2:x3;
    const float vi = (g==0)?own:(g==1)?r1:(g==2)?r2:r3;
    const float vf = (g==1)?own:(g==0)?r1:(g==3)?r2:r3;
    const float vg = (g==2)?own:(g==3)?r1:(g==0)?r2:r3;
    const float vo = (g==3)?own:(g==2)?r1:(g==1)?r2:r3;
    const float ig = sigm(vi), fg = sigm(vf), gt = tanh_(vg), og = sigm(vo);
    cstate = fg * cstate + ig * gt;
    const float hval = og * tanh_(cstate);
    // fused span-mean pooling
    if (s != curspan){
      if (curspan >= 0) sums[((size_t)bstar * NS_ + curspan) * H_ + j] = pool;
      pool = 0.f; curspan = s;
    }
    if (s >= 0) pool += hval;
    // stage h_t and publish
    Hs[bstar * 16 + jl] = f2bf(hval);
    __syncthreads();
    if (tid < 32){   // wave 0: 32 coalesced coherent 16B stores (plain layout)
      const int sb = tid >> 1, half = tid & 1;
      u32x4 v = *(const u32x4*)((const unsigned char*)Hs + tid * 16);
      store_coh16((unsigned char*)hbuf + (p ^ 1) * 32768 + sb * 2048 + cu * 32 + half * 16, v);
    }
    if (tid == 0){
      asm volatile("s_waitcnt vmcnt(0)" ::: "memory");  // slice committed at LLC
      __hip_atomic_store(tags + (size_t)((t + 1) & 1) * 1024 + (size_t)cu * 16,
                         (unsigned int)(t + 1), __ATOMIC_RELAXED, __HIP_MEMORY_SCOPE_AGENT);
    }
    // no trailing syncthreads: waves free-run into next poll (tag ordering protects Hs)
  }
  if (curspan >= 0) sums[((size_t)bstar * NS_ + curspan) * H_ + j] = pool;
}

// ---------------- block reduce helper ----------------
DEV float block_sum(float v, float* red, int tid){
  #pragma unroll
  for (int d = 1; d < 64; d <<= 1) v += __shfl_xor(v, d, 64);
  if ((tid & 63) == 0) red[tid >> 6] = v;
  __syncthreads();
  const float r = red[0] + red[1] + red[2] + red[3];
  __syncthreads();
  return r;
}

// ---------------- pooled mean + LayerNorm -> mean_vec (bf16 + f32) ----------------
__global__ __launch_bounds__(256) void k_poolln(const float* __restrict__ sums,
    const int* __restrict__ head, const int* __restrict__ tail,
    const float* __restrict__ gamma, const float* __restrict__ beta,
    unsigned short* __restrict__ mvb, float* __restrict__ mvf){
  __shared__ float red[4];
  const int m = blockIdx.x, tid = threadIdx.x;
  const float inv = 1.f / (float)(tail[m] - head[m] - 1);
  float4 x = *(const float4*)(sums + (size_t)m * H_ + tid * 4);
  x.x *= inv; x.y *= inv; x.z *= inv; x.w *= inv;
  const float mu = block_sum(x.x + x.y + x.z + x.w, red, tid) * (1.f / (float)H_);
  const float d0 = x.x - mu, d1 = x.y - mu, d2 = x.z - mu, d3 = x.w - mu;
  const float var = block_sum(d0*d0 + d1*d1 + d2*d2 + d3*d3, red, tid) * (1.f / (float)H_);
  const float rs = rsqrtf(var + 1e-7f);
  float4 gm = *(const float4*)(gamma + tid * 4);
  float4 bt = *(const float4*)(beta + tid * 4);
  float4 o; o.x = d0*rs*gm.x + bt.x; o.y = d1*rs*gm.y + bt.y;
  o.z = d2*rs*gm.z + bt.z; o.w = d3*rs*gm.w + bt.w;
  *(float4*)(mvf + (size_t)m * H_ + tid * 4) = o;
  ushort4 u; u.x = f2bf(o.x); u.y = f2bf(o.y); u.z = f2bf(o.z); u.w = f2bf(o.w);
  *(ushort4*)(mvb + (size_t)m * H_ + tid * 4) = u;
}

// ---------------- generic small GEMM: C[M][Nn] = A_bf16[M][1024] @ Bw[Nn][1024]^T + bias ------
template<int OUT_BF16>
__global__ __launch_bounds__(256) void k_gemm2(const unsigned short* __restrict__ A,
    const float* __restrict__ Bw, const float* __restrict__ bias,
    float* __restrict__ Cf, unsigned short* __restrict__ Cb, int Nn){
  const int nb = blockIdx.x, mb = blockIdx.y;
  __shared__ __align__(16) unsigned short As[128 * 40];
  __shared__ __align__(16) unsigned short Bs[128 * 40];
  const int tid = threadIdx.x, w = tid >> 6, l = tid & 63;
  const int wm = (w >> 1) * 64, wn = (w & 1) * 64;
  const int cl = l & 15, bg = l >> 4;
  f32x4 acc[4][4] = {};
  const int m0 = mb * 128, n0 = nb * 128;
  const int srow = tid >> 1, skq = (tid & 1) * 16;
  const unsigned short* Asrc = A + (size_t)(m0 + srow) * 1024 + skq;
  const float* Bsrc = Bw + (size_t)(n0 + srow) * 1024 + skq;
  for (int k0 = 0; k0 < 1024; k0 += 32){
    uint4 av0 = *(const uint4*)(Asrc + k0);
    uint4 av1 = *(const uint4*)(Asrc + k0 + 8);
    *(uint4*)(As + srow * 40 + skq) = av0;
    *(uint4*)(As + srow * 40 + skq + 8) = av1;
    #pragma unroll
    for (int q = 0; q < 4; ++q){
      float4 b = *(const float4*)(Bsrc + k0 + q * 4);
      ushort4 ub; ub.x = f2bf(b.x); ub.y = f2bf(b.y); ub.z = f2bf(b.z); ub.w = f2bf(b.w);
      *(ushort4*)(Bs + srow * 40 + skq + q * 4) = ub;
    }
    __syncthreads();
    short8 af[4], bf[4];
    const int kq = bg * 8;
    #pragma unroll
    for (int i = 0; i < 4; ++i) af[i] = *(const short8*)(As + (wm + i * 16 + cl) * 40 + kq);
    #pragma unroll
    for (int i = 0; i < 4; ++i) bf[i] = *(const short8*)(Bs + (wn + i * 16 + cl) * 40 + kq);
    #pragma unroll
    for (int mi = 0; mi < 4; ++mi)
      #pragma unroll
      for (int ni = 0; ni < 4; ++ni)
        acc[mi][ni] = __builtin_amdgcn_mfma_f32_16x16x32_bf16(af[mi], bf[ni], acc[mi][ni], 0, 0, 0);
    __syncthreads();
  }
  #pragma unroll
  for (int ni = 0; ni < 4; ++ni){
    const int c = n0 + wn + ni * 16 + cl;
    const float bsv = bias ? bias[c] : 0.f;
    #pragma unroll
    for (int mi = 0; mi < 4; ++mi){
      const int m = m0 + wm + mi * 16 + bg * 4;
      const float v0 = acc[mi][ni].x + bsv, v1 = acc[mi][ni].y + bsv;
      const float v2 = acc[mi][ni].z + bsv, v3 = acc[mi][ni].w + bsv;
      if (OUT_BF16){
        Cb[(size_t)(m + 0) * Nn + c] = f2bf(v0);
        Cb[(size_t)(m + 1) * Nn + c] = f2bf(v1);
        Cb[(size_t)(m + 2) * Nn + c] = f2bf(v2);
        Cb[(size_t)(m + 3) * Nn + c] = f2bf(v3);
      } else {
        Cf[(size_t)(m + 0) * Nn + c] = v0;
        Cf[(size_t)(m + 1) * Nn + c] = v1;
        Cf[(size_t)(m + 2) * Nn + c] = v2;
        Cf[(size_t)(m + 3) * Nn + c] = v3;
      }
    }
  }
}

// ---------------- span attention: one block per (b, head) ----------------
__global__ __launch_bounds__(256) void k_attn(const unsigned short* __restrict__ qb,
    const unsigned short* __restrict__ kb, const unsigned short* __restrict__ vb,
    const int* __restrict__ mask, unsigned short* __restrict__ ctx){
  const int bh = blockIdx.x, b = bh >> 4, hd = bh & 15;
  __shared__ float Q[32][64], K[32][64], V[32][64], Sc[32][33];
  __shared__ int msk[32];
  const int tid = threadIdx.x;
  const int row = tid >> 3, d0 = (tid & 7) * 8;
  {
    const size_t base = (size_t)(b * NS_ + row) * H_ + hd * 64 + d0;
    uint4 vq = *(const uint4*)(qb + base);
    uint4 vk = *(const uint4*)(kb + base);
    uint4 vv = *(const uint4*)(vb + base);
    const unsigned int wq[4] = {vq.x, vq.y, vq.z, vq.w};
    const unsigned int wk[4] = {vk.x, vk.y, vk.z, vk.w};
    const unsigned int wv[4] = {vv.x, vv.y, vv.z, vv.w};
    #pragma unroll
    for (int i = 0; i < 4; ++i){
      Q[row][d0 + 2*i]     = bf2f((unsigned short)(wq[i] & 0xffff));
      Q[row][d0 + 2*i + 1] = bf2f((unsigned short)(wq[i] >> 16));
      K[row][d0 + 2*i]     = bf2f((unsigned short)(wk[i] & 0xffff));
      K[row][d0 + 2*i + 1] = bf2f((unsigned short)(wk[i] >> 16));
      V[row][d0 + 2*i]     = bf2f((unsigned short)(wv[i] & 0xffff));
      V[row][d0 + 2*i + 1] = bf2f((unsigned short)(wv[i] >> 16));
    }
  }
  if (tid < 32) msk[tid] = mask[b * NS_ + tid];
  __syncthreads();
  {
    const int qi = tid >> 3, kb0 = (tid & 7) * 4;
    for (int kk = kb0; kk < kb0 + 4; ++kk){
      float s = 0.f;
      #pragma unroll
      for (int d = 0; d < 64; ++d) s += Q[qi][d] * K[kk][d];
      s *= 0.125f;
      if (!msk[qi] || !msk[kk]) s = -3.402823466e38f;
      Sc[qi][kk] = s;
    }
  }
  __syncthreads();
  if (tid < 32){
    float mx = -3.402823466e38f;
    for (int kk = 0; kk < 32; ++kk) mx = fmaxf(mx, Sc[tid][kk]);
    float sum = 0.f;
    for (int kk = 0; kk < 32; ++kk){
      const float e = __expf(Sc[tid][kk] - mx);
      Sc[tid][kk] = e; sum += e;
    }
    const float isum = 1.f / sum;
    for (int kk = 0; kk < 32; ++kk){
      float pv = Sc[tid][kk] * isum;
      if (!msk[tid] || !msk[kk]) pv = 0.f;
      Sc[tid][kk] = pv;
    }
  }
  __syncthreads();
  float o[8] = {0,0,0,0,0,0,0,0};
  for (int kk = 0; kk < 32; ++kk){
    const float p = Sc[row][kk];
    #pragma unroll
    for (int i = 0; i < 8; ++i) o[i] += p * V[kk][d0 + i];
  }
  ushort4 oA, oB;
  oA.x = f2bf(o[0]); oA.y = f2bf(o[1]); oA.z = f2bf(o[2]); oA.w = f2bf(o[3]);
  oB.x = f2bf(o[4]); oB.y = f2bf(o[5]); oB.z = f2bf(o[6]); oB.w = f2bf(o[7]);
  unsigned short* cp = ctx + (size_t)(b * NS_ + row) * H_ + hd * 64 + d0;
  *(ushort4*)(cp) = oA;
  *(ushort4*)(cp + 4) = oB;
}

// ---------------- residual + LayerNorm -> attn_out (f32) ----------------
__global__ __launch_bounds__(256) void k_residln(const float* __restrict__ wo,
    const float* __restrict__ mvf, const float* __restrict__ gamma,
    const float* __restrict__ beta, float* __restrict__ aof){
  __shared__ float red[4];
  const int m = blockIdx.x, tid = threadIdx.x;
  float4 a = *(const float4*)(wo + (size_t)m * H_ + tid * 4);
  float4 r = *(const float4*)(mvf + (size_t)m * H_ + tid * 4);
  float4 x; x.x = a.x + r.x; x.y = a.y + r.y; x.z = a.z + r.z; x.w = a.w + r.w;
  const float mu = block_sum(x.x + x.y + x.z + x.w, red, tid) * (1.f / (float)H_);
  const float d0 = x.x - mu, d1 = x.y - mu, d2 = x.z - mu, d3 = x.w - mu;
  const float var = block_sum(d0*d0 + d1*d1 + d2*d2 + d3*d3, red, tid) * (1.f / (float)H_);
  const float rs = rsqrtf(var + 1e-7f);
  float4 gm = *(const float4*)(gamma + tid * 4);
  float4 bt = *(const float4*)(beta + tid * 4);
  float4 o; o.x = d0*rs*gm.x + bt.x; o.y = d1*rs*gm.y + bt.y;
  o.z = d2*rs*gm.z + bt.z; o.w = d3*rs*gm.w + bt.w;
  *(float4*)(aof + (size_t)m * H_ + tid * 4) = o;
}

// ---------------- classifier: logits[m][l] ----------------
__global__ __launch_bounds__(64) void k_clf(const float* __restrict__ ao,
    const float* __restrict__ Wc, const float* __restrict__ bc, float* __restrict__ out){
  const int m = blockIdx.x, l = threadIdx.x;
  const float* a = ao + (size_t)m * H_ + l * 16;
  float av[16];
  #pragma unroll
  for (int i = 0; i < 4; ++i){
    float4 v = *(const float4*)(a + i * 4);
    av[i*4+0] = v.x; av[i*4+1] = v.y; av[i*4+2] = v.z; av[i*4+3] = v.w;
  }
  float p[5];
  #pragma unroll
  for (int c = 0; c < 5; ++c){
    const float* wr = Wc + (size_t)c * H_ + l * 16;
    float s = 0.f;
    #pragma unroll
    for (int i = 0; i < 4; ++i){
      float4 v = *(const float4*)(wr + i * 4);
      s += av[i*4+0]*v.x + av[i*4+1]*v.y + av[i*4+2]*v.z + av[i*4+3]*v.w;
    }
    p[c] = s;
  }
  #pragma unroll
  for (int d = 1; d < 64; d <<= 1){
    #pragma unroll
    for (int c = 0; c < 5; ++c) p[c] += __shfl_xor(p[c], d, 64);
  }
  if (l == 0){
    #pragma unroll
    for (int c = 0; c < 5; ++c) out[m * L_ + c] = p[c] + bc[c];
  }
}

extern "C" void kernel_launch(void* const* d_in, const int* in_sizes, int n_in,
                              void* d_out, int out_size, void* d_ws, size_t ws_size,
                              hipStream_t stream){
  (void)in_sizes; (void)n_in; (void)out_size; (void)ws_size;
  const float* enc  = (const float*)d_in[0];
  const float* Wih  = (const float*)d_in[1];
  const float* Whh  = (const float*)d_in[2];
  const float* bih  = (const float*)d_in[3];
  const float* bhh  = (const float*)d_in[4];
  const float* lng  = (const float*)d_in[5];
  const float* lnb  = (const float*)d_in[6];
  const float* Wq   = (const float*)d_in[7];
  const float* bq   = (const float*)d_in[8];
  const float* Wk   = (const float*)d_in[9];
  const float* bk   = (const float*)d_in[10];
  const float* Wv   = (const float*)d_in[11];
  const float* bv   = (const float*)d_in[12];
  const float* Wo   = (const float*)d_in[13];
  const float* bo   = (const float*)d_in[14];
  const float* alng = (const float*)d_in[15];
  const float* alnb = (const float*)d_in[16];
  const float* clfW = (const float*)d_in[17];
  const float* clfb = (const float*)d_in[18];
  const int* shead  = (const int*)d_in[19];
  const int* stail  = (const int*)d_in[20];
  const int* smask  = (const int*)d_in[21];
  float* out = (float*)d_out;
  unsigned char* ws = (unsigned char*)d_ws;

  size_t cur = 0;
  auto alloc = [&](size_t sz){ size_t r = cur; cur = (cur + sz + 255) & ~(size_t)255; return r; };
  const size_t off_gx   = alloc((size_t)S_ * G4H * B_ * 2);     // 134 MB bf16, per-block layout
  const size_t off_hbuf = alloc(2 * (size_t)B_ * H_ * 2);       // 64 KB, 2 parities, plain [b][j]
  const size_t off_tags = alloc(2 * 1024 * 4);                  // 8 KB tag flags (64B stride)
  const size_t off_span = alloc((size_t)B_ * S_ * 4);
  const size_t off_sums = alloc((size_t)B_ * NS_ * H_ * 4);
  const size_t off_mvb  = alloc((size_t)B_ * NS_ * H_ * 2);
  const size_t off_mvf  = alloc((size_t)B_ * NS_ * H_ * 4);
  const size_t off_q    = alloc((size_t)B_ * NS_ * H_ * 2);
  const size_t off_k    = alloc((size_t)B_ * NS_ * H_ * 2);
  const size_t off_v    = alloc((size_t)B_ * NS_ * H_ * 2);
  const size_t off_ctx  = alloc((size_t)B_ * NS_ * H_ * 2);
  const size_t off_wo   = alloc((size_t)B_ * NS_ * H_ * 4);
  const size_t off_ao   = alloc((size_t)B_ * NS_ * H_ * 4);

  unsigned short* gx   = (unsigned short*)(ws + off_gx);
  unsigned short* hbuf = (unsigned short*)(ws + off_hbuf);
  unsigned int*   tags = (unsigned int*)(ws + off_tags);
  int*            span = (int*)(ws + off_span);
  float*          sums = (float*)(ws + off_sums);
  unsigned short* mvb  = (unsigned short*)(ws + off_mvb);
  float*          mvf  = (float*)(ws + off_mvf);
  unsigned short* qb   = (unsigned short*)(ws + off_q);
  unsigned short* kbp  = (unsigned short*)(ws + off_k);
  unsigned short* vbp  = (unsigned short*)(ws + off_v);
  unsigned short* ctx  = (unsigned short*)(ws + off_ctx);
  float*          wob  = (float*)(ws + off_wo);
  float*          aof  = (float*)(ws + off_ao);

  (void)hipMemsetAsync(hbuf, 0, 2 * (size_t)B_ * H_ * 2, stream);
  (void)hipMemsetAsync(tags, 0, 2 * 1024 * 4, stream);
  (void)hipMemsetAsync(sums, 0, (size_t)B_ * NS_ * H_ * 4, stream);

  k_spanof<<<B_, 256, 0, stream>>>(shead, stail, span);
  k_gates<<<dim3(32, 128), 256, 0, stream>>>(enc, Wih, bih, bhh, gx);

  k_lstm<<<LSTM_GRID, 256, 0, stream>>>(Whh, gx, span, hbuf, tags, sums);

  k_poolln<<<B_ * NS_, 256, 0, stream>>>(sums, shead, stail, lng, lnb, mvb, mvf);
  k_gemm2<1><<<dim3(8, 4), 256, 0, stream>>>(mvb, Wq, bq, nullptr, qb, 1024);
  k_gemm2<1><<<dim3(8, 4), 256, 0, stream>>>(mvb, Wk, bk, nullptr, kbp, 1024);
  k_gemm2<1><<<dim3(8, 4), 256, 0, stream>>>(mvb, Wv, bv, nullptr, vbp, 1024);
  k_attn<<<B_ * HEADS_, 256, 0, stream>>>(qb, kbp, vbp, smask, ctx);
  k_gemm2<0><<<dim3(8, 4), 256, 0, stream>>>(ctx, Wo, bo, wob, nullptr, 1024);
  k_residln<<<B_ * NS_, 256, 0, stream>>>(wob, mvf, alng, alnb, aof);
  k_clf<<<B_ * NS_, 64, 0, stream>>>(aof, clfW, clfb, out);
}

// Round 6
// 3954.931 us; speedup vs baseline: 1.6184x; 1.6184x over previous
//
#include <hip/hip_runtime.h>
#include <hip/hip_bf16.h>

#define DEV __device__ __forceinline__

typedef __attribute__((ext_vector_type(8))) short short8;
typedef __attribute__((ext_vector_type(4))) float f32x4;
typedef __attribute__((ext_vector_type(4))) unsigned int u32x4;

static constexpr int B_ = 16, S_ = 1024, H_ = 1024, NS_ = 32, HEADS_ = 16, L_ = 5;
static constexpr int G4H = 4096;
static constexpr int LSTM_GRID = 64;

DEV unsigned short f2bf(float f){
  union { float f; unsigned int i; } u; u.f = f;
  unsigned int r = (u.i + 0x7fffu + ((u.i >> 16) & 1u)) >> 16;
  return (unsigned short)r;
}
DEV float bf2f(unsigned short h){
  union { unsigned int i; float f; } u; u.i = ((unsigned int)h) << 16;
  return u.f;
}
DEV float sigm(float x){ return 1.f / (1.f + __expf(-x)); }
DEV float tanh_(float x){
  x = fminf(30.f, fmaxf(-30.f, x));
  float e = __expf(-2.f * x);
  return (1.f - e) / (1.f + e);
}

// coherent (LLC-level) 16B load/store: bypass L1+L2 so cross-XCD exchange needs NO cache fences
DEV u32x4 load_coh16(const void* p){
  u32x4 r;
  asm volatile("global_load_dwordx4 %0, %1, off sc0 sc1" : "=v"(r) : "v"(p));
  return r;
}
DEV void store_coh16(void* p, u32x4 v){
  asm volatile("global_store_dwordx4 %0, %1, off sc0 sc1" :: "v"(p), "v"(v) : "memory");
}

// ---------------- span_of map: span_of[b][t] = span index or -1 ----------------
__global__ void k_spanof(const int* __restrict__ head, const int* __restrict__ tail,
                         int* __restrict__ spanof){
  const int b = blockIdx.x;
  for (int t = threadIdx.x; t < S_; t += blockDim.x) spanof[b * S_ + t] = -1;
  __syncthreads();
  if (threadIdx.x < NS_){
    const int n = threadIdx.x;
    const int h = head[b * NS_ + n], tl = tail[b * NS_ + n];
    for (int t = h + 1; t < tl; ++t) spanof[b * S_ + t] = n;
  }
}

// ---------------- gates_x GEMM -> gx in per-LSTM-block layout ----------------
// gx ushort4 index: ((t*64 + cu)*64 + (w*16 + n))*4 + bg   (contiguous 2KB per block per step)
__global__ __launch_bounds__(256) void k_gates(const float* __restrict__ enc,
    const float* __restrict__ Wih, const float* __restrict__ bih,
    const float* __restrict__ bhh, unsigned short* __restrict__ gx){
  const int nb = blockIdx.x;   // 0..31  (N=4096 / 128)
  const int mb = blockIdx.y;   // 0..127 (M=16384 / 128); m = t*16 + b
  __shared__ __align__(16) unsigned short As[128 * 40];
  __shared__ __align__(16) unsigned short Bs[128 * 40];
  const int tid = threadIdx.x, w = tid >> 6, l = tid & 63;
  const int wm = (w >> 1) * 64, wn = (w & 1) * 64;
  const int cl = l & 15, bg = l >> 4;
  f32x4 acc[4][4] = {};
  const int t0 = mb * 8, n0 = nb * 128;
  const int srow = tid >> 1, skq = (tid & 1) * 16;
  const int sb = srow & 15, stt = t0 + (srow >> 4);
  const float* Asrc = enc + ((size_t)sb * S_ + stt) * H_ + skq;
  const float* Bsrc = Wih + (size_t)(n0 + srow) * H_ + skq;
  for (int k0 = 0; k0 < H_; k0 += 32){
    #pragma unroll
    for (int q = 0; q < 4; ++q){
      float4 a = *(const float4*)(Asrc + k0 + q * 4);
      float4 b = *(const float4*)(Bsrc + k0 + q * 4);
      ushort4 ua; ua.x = f2bf(a.x); ua.y = f2bf(a.y); ua.z = f2bf(a.z); ua.w = f2bf(a.w);
      ushort4 ub; ub.x = f2bf(b.x); ub.y = f2bf(b.y); ub.z = f2bf(b.z); ub.w = f2bf(b.w);
      *(ushort4*)(As + srow * 40 + skq + q * 4) = ua;
      *(ushort4*)(Bs + srow * 40 + skq + q * 4) = ub;
    }
    __syncthreads();
    short8 af[4], bf[4];
    const int kq = bg * 8;
    #pragma unroll
    for (int i = 0; i < 4; ++i) af[i] = *(const short8*)(As + (wm + i * 16 + cl) * 40 + kq);
    #pragma unroll
    for (int i = 0; i < 4; ++i) bf[i] = *(const short8*)(Bs + (wn + i * 16 + cl) * 40 + kq);
    #pragma unroll
    for (int mi = 0; mi < 4; ++mi)
      #pragma unroll
      for (int ni = 0; ni < 4; ++ni)
        acc[mi][ni] = __builtin_amdgcn_mfma_f32_16x16x32_bf16(af[mi], bf[ni], acc[mi][ni], 0, 0, 0);
    __syncthreads();
  }
  #pragma unroll
  for (int ni = 0; ni < 4; ++ni){
    const int c = n0 + wn + ni * 16 + cl;
    const float bias = bih[c] + bhh[c];
    const int g = c >> 10, j = c & 1023;
    const int cuq = j >> 4, wq = (j >> 2) & 3, jjq = j & 3;
    const int nq = jjq * 4 + g;
    #pragma unroll
    for (int mi = 0; mi < 4; ++mi){
      const int tg = t0 + ((wm + mi * 16) >> 4);
      ushort4 o;
      o.x = f2bf(acc[mi][ni].x + bias);
      o.y = f2bf(acc[mi][ni].y + bias);
      o.z = f2bf(acc[mi][ni].z + bias);
      o.w = f2bf(acc[mi][ni].w + bias);
      const size_t u4i = (((size_t)tg * 64 + cuq) * 64 + (wq * 16 + nq)) * 4 + bg;
      *((ushort4*)gx + u4i) = o;
    }
  }
}

// ---------------- persistent LSTM + fused span pooling ----------------
// 64 blocks x 256 thr, 1 block/CU. W_hh fragments in VGPRs (128/lane).
// h: producer stores SWIZZLED global image (coherent), consumer raw-copies 32KB -> LDS
// (coalesced, 128B/lane), reads fragments with XOR-after-add swizzle (R4-proven).
// Distributed tag-flag barrier (R5-proven): tags[parity][64], 64B stride.
__global__ __launch_bounds__(256, 1) void k_lstm(const float* __restrict__ Whh,
    const unsigned short* __restrict__ gx, const int* __restrict__ spanof,
    unsigned short* __restrict__ hbuf, unsigned int* __restrict__ tags,
    float* __restrict__ sums){
  __shared__ __align__(16) unsigned char Himg[32768];   // swizzled h image
  __shared__ __align__(16) unsigned short Hs[256];      // [b][jl] staging
  const int cu = blockIdx.x, tid = threadIdx.x;
  const int w = tid >> 6, l = tid & 63;
  const int n = l & 15, bg = l >> 4;
  const int g = n & 3, jj = n >> 2;
  const int j = cu * 16 + w * 4 + jj;    // my h column
  const int bstar = bg * 4 + g;          // my owned batch
  const int jl = w * 4 + jj;             // local h column

  // ---- stage my W_hh B-fragments: col = g*H + j, k = kk*32 + bg*8 + [0..8) ----
  short8 wr[32];
  {
    const float* wsrc = Whh + (size_t)(g * H_ + j) * H_ + bg * 8;
    #pragma unroll
    for (int kk = 0; kk < 32; ++kk){
      float4 x = *(const float4*)(wsrc + kk * 32);
      float4 y = *(const float4*)(wsrc + kk * 32 + 4);
      short8 v;
      v[0] = (short)f2bf(x.x); v[1] = (short)f2bf(x.y);
      v[2] = (short)f2bf(x.z); v[3] = (short)f2bf(x.w);
      v[4] = (short)f2bf(y.x); v[5] = (short)f2bf(y.y);
      v[6] = (short)f2bf(y.z); v[7] = (short)f2bf(y.w);
      wr[kk] = v;
    }
  }

  // h fragment read addressing (XOR applied AFTER adding kk*64 — bit6 overlap!)
  const unsigned int abase = (unsigned)(n * 2048 + bg * 16);
  const unsigned int aswz  = (unsigned)((n & 7) << 4);

  const ushort4* gxp = (const ushort4*)gx + ((size_t)cu * 64 + w * 16 + n) * 4 + bg;
  const int* sp = spanof + (size_t)bstar * S_;

  float cstate = 0.f, pool = 0.f;
  int curspan = -1;

  for (int t = 0; t < S_; ++t){
    const int p = t & 1;
    const ushort4 gxv = gxp[(size_t)t * 16384];     // static data, issue early
    const int s = sp[t];
    { // poll distributed tags: lane l watches block l
      const unsigned int* tp = tags + (size_t)p * 1024 + (size_t)l * 16;
      unsigned int v = __hip_atomic_load(tp, __ATOMIC_RELAXED, __HIP_MEMORY_SCOPE_AGENT);
      int guard = 0;
      while (!__all(v == (unsigned int)t)){
        __builtin_amdgcn_s_sleep(1);
        v = __hip_atomic_load(tp, __ATOMIC_RELAXED, __HIP_MEMORY_SCOPE_AGENT);
        if (++guard > 2000000) break;
      }
    }
    { // coalesced coherent 32KB image load -> LDS raw copy (one copy per block)
      const unsigned char* hsrc = (const unsigned char*)hbuf + p * 32768 + w * 8192 + l * 16;
      u32x4 v0 = load_coh16(hsrc + 0 * 1024);
      u32x4 v1 = load_coh16(hsrc + 1 * 1024);
      u32x4 v2 = load_coh16(hsrc + 2 * 1024);
      u32x4 v3 = load_coh16(hsrc + 3 * 1024);
      u32x4 v4 = load_coh16(hsrc + 4 * 1024);
      u32x4 v5 = load_coh16(hsrc + 5 * 1024);
      u32x4 v6 = load_coh16(hsrc + 6 * 1024);
      u32x4 v7 = load_coh16(hsrc + 7 * 1024);
      asm volatile("s_waitcnt vmcnt(0)" ::: "memory");
      __builtin_amdgcn_sched_barrier(0);
      unsigned char* hdst = Himg + w * 8192 + l * 16;
      *(u32x4*)(hdst + 0 * 1024) = v0;
      *(u32x4*)(hdst + 1 * 1024) = v1;
      *(u32x4*)(hdst + 2 * 1024) = v2;
      *(u32x4*)(hdst + 3 * 1024) = v3;
      *(u32x4*)(hdst + 4 * 1024) = v4;
      *(u32x4*)(hdst + 5 * 1024) = v5;
      *(u32x4*)(hdst + 6 * 1024) = v6;
      *(u32x4*)(hdst + 7 * 1024) = v7;
    }
    __syncthreads();   // sync A: image ready
    f32x4 a0 = {0,0,0,0}, a1 = {0,0,0,0}, a2 = {0,0,0,0}, a3 = {0,0,0,0};
    #pragma unroll
    for (int kk = 0; kk < 32; kk += 4){
      short8 h0 = *(const short8*)(Himg + ((abase + (kk + 0) * 64) ^ aswz));
      a0 = __builtin_amdgcn_mfma_f32_16x16x32_bf16(h0, wr[kk + 0], a0, 0, 0, 0);
      short8 h1 = *(const short8*)(Himg + ((abase + (kk + 1) * 64) ^ aswz));
      a1 = __builtin_amdgcn_mfma_f32_16x16x32_bf16(h1, wr[kk + 1], a1, 0, 0, 0);
      short8 h2 = *(const short8*)(Himg + ((abase + (kk + 2) * 64) ^ aswz));
      a2 = __builtin_amdgcn_mfma_f32_16x16x32_bf16(h2, wr[kk + 2], a2, 0, 0, 0);
      short8 h3 = *(const short8*)(Himg + ((abase + (kk + 3) * 64) ^ aswz));
      a3 = __builtin_amdgcn_mfma_f32_16x16x32_bf16(h3, wr[kk + 3], a3, 0, 0, 0);
    }
    f32x4 acc = (a0 + a1) + (a2 + a3);
    const float x0 = acc.x + bf2f(gxv.x);
    const float x1 = acc.y + bf2f(gxv.y);
    const float x2 = acc.z + bf2f(gxv.z);
    const float x3 = acc.w + bf2f(gxv.w);
    // 4-lane transpose: gather all 4 gate types for batch bstar
    const float s1 = (g==0)?x1:(g==1)?x0:(g==2)?x3:x2;   // beta = g^1
    const float s2 = (g==0)?x2:(g==1)?x3:(g==2)?x0:x1;   // beta = g^2
    const float s3 = (g==0)?x3:(g==1)?x2:(g==2)?x1:x0;   // beta = g^3
    const float r1 = __shfl_xor(s1, 1, 64);
    const float r2 = __shfl_xor(s2, 2, 64);
    const float r3 = __shfl_xor(s3, 3, 64);
    const float own = (g==0)?x0:(g==1)?x1:(g==2)?x2:x3;
    const float vi = (g==0)?own:(g==1)?r1:(g==2)?r2:r3;
    const float vf = (g==1)?own:(g==0)?r1:(g==3)?r2:r3;
    const float vg = (g==2)?own:(g==3)?r1:(g==0)?r2:r3;
    const float vo = (g==3)?own:(g==2)?r1:(g==1)?r2:r3;
    const float ig = sigm(vi), fg = sigm(vf), gt = tanh_(vg), og = sigm(vo);
    cstate = fg * cstate + ig * gt;
    const float hval = og * tanh_(cstate);
    // stage h_t and publish ASAP (pooling bookkeeping happens after)
    Hs[bstar * 16 + jl] = f2bf(hval);
    __syncthreads();   // sync B: staging ready; also orders Himg reads(t) vs writes(t+1)
    if (tid < 32){     // wave 0: 32 coalesced coherent 16B stores into SWIZZLED image
      const int sb = tid >> 1, half = tid & 1;
      const unsigned key = (unsigned)((sb & 7) << 4);
      const unsigned off = (unsigned)(sb * 2048)
          + ((unsigned)(cu * 32) ^ (key & 0x60))
          + ((unsigned)(half * 16) ^ (key & 0x10));
      u32x4 v = *(const u32x4*)((const unsigned char*)Hs + tid * 16);
      store_coh16((unsigned char*)hbuf + (p ^ 1) * 32768 + off, v);
    }
    if (tid == 0){
      asm volatile("s_waitcnt vmcnt(0)" ::: "memory");  // slice committed at LLC
      __hip_atomic_store(tags + (size_t)((t + 1) & 1) * 1024 + (size_t)cu * 16,
                         (unsigned int)(t + 1), __ATOMIC_RELAXED, __HIP_MEMORY_SCOPE_AGENT);
    }
    // fused span-mean pooling (after publish, overlaps store latency)
    if (s != curspan){
      if (curspan >= 0) sums[((size_t)bstar * NS_ + curspan) * H_ + j] = pool;
      pool = 0.f; curspan = s;
    }
    if (s >= 0) pool += hval;
  }
  if (curspan >= 0) sums[((size_t)bstar * NS_ + curspan) * H_ + j] = pool;
}

// ---------------- block reduce helper ----------------
DEV float block_sum(float v, float* red, int tid){
  #pragma unroll
  for (int d = 1; d < 64; d <<= 1) v += __shfl_xor(v, d, 64);
  if ((tid & 63) == 0) red[tid >> 6] = v;
  __syncthreads();
  const float r = red[0] + red[1] + red[2] + red[3];
  __syncthreads();
  return r;
}

// ---------------- pooled mean + LayerNorm -> mean_vec (bf16 + f32) ----------------
__global__ __launch_bounds__(256) void k_poolln(const float* __restrict__ sums,
    const int* __restrict__ head, const int* __restrict__ tail,
    const float* __restrict__ gamma, const float* __restrict__ beta,
    unsigned short* __restrict__ mvb, float* __restrict__ mvf){
  __shared__ float red[4];
  const int m = blockIdx.x, tid = threadIdx.x;
  const float inv = 1.f / (float)(tail[m] - head[m] - 1);
  float4 x = *(const float4*)(sums + (size_t)m * H_ + tid * 4);
  x.x *= inv; x.y *= inv; x.z *= inv; x.w *= inv;
  const float mu = block_sum(x.x + x.y + x.z + x.w, red, tid) * (1.f / (float)H_);
  const float d0 = x.x - mu, d1 = x.y - mu, d2 = x.z - mu, d3 = x.w - mu;
  const float var = block_sum(d0*d0 + d1*d1 + d2*d2 + d3*d3, red, tid) * (1.f / (float)H_);
  const float rs = rsqrtf(var + 1e-7f);
  float4 gm = *(const float4*)(gamma + tid * 4);
  float4 bt = *(const float4*)(beta + tid * 4);
  float4 o; o.x = d0*rs*gm.x + bt.x; o.y = d1*rs*gm.y + bt.y;
  o.z = d2*rs*gm.z + bt.z; o.w = d3*rs*gm.w + bt.w;
  *(float4*)(mvf + (size_t)m * H_ + tid * 4) = o;
  ushort4 u; u.x = f2bf(o.x); u.y = f2bf(o.y); u.z = f2bf(o.z); u.w = f2bf(o.w);
  *(ushort4*)(mvb + (size_t)m * H_ + tid * 4) = u;
}

// ---------------- generic small GEMM: C[M][Nn] = A_bf16[M][1024] @ Bw[Nn][1024]^T + bias ------
template<int OUT_BF16>
__global__ __launch_bounds__(256) void k_gemm2(const unsigned short* __restrict__ A,
    const float* __restrict__ Bw, const float* __restrict__ bias,
    float* __restrict__ Cf, unsigned short* __restrict__ Cb, int Nn){
  const int nb = blockIdx.x, mb = blockIdx.y;
  __shared__ __align__(16) unsigned short As[128 * 40];
  __shared__ __align__(16) unsigned short Bs[128 * 40];
  const int tid = threadIdx.x, w = tid >> 6, l = tid & 63;
  const int wm = (w >> 1) * 64, wn = (w & 1) * 64;
  const int cl = l & 15, bg = l >> 4;
  f32x4 acc[4][4] = {};
  const int m0 = mb * 128, n0 = nb * 128;
  const int srow = tid >> 1, skq = (tid & 1) * 16;
  const unsigned short* Asrc = A + (size_t)(m0 + srow) * 1024 + skq;
  const float* Bsrc = Bw + (size_t)(n0 + srow) * 1024 + skq;
  for (int k0 = 0; k0 < 1024; k0 += 32){
    uint4 av0 = *(const uint4*)(Asrc + k0);
    uint4 av1 = *(const uint4*)(Asrc + k0 + 8);
    *(uint4*)(As + srow * 40 + skq) = av0;
    *(uint4*)(As + srow * 40 + skq + 8) = av1;
    #pragma unroll
    for (int q = 0; q < 4; ++q){
      float4 b = *(const float4*)(Bsrc + k0 + q * 4);
      ushort4 ub; ub.x = f2bf(b.x); ub.y = f2bf(b.y); ub.z = f2bf(b.z); ub.w = f2bf(b.w);
      *(ushort4*)(Bs + srow * 40 + skq + q * 4) = ub;
    }
    __syncthreads();
    short8 af[4], bf[4];
    const int kq = bg * 8;
    #pragma unroll
    for (int i = 0; i < 4; ++i) af[i] = *(const short8*)(As + (wm + i * 16 + cl) * 40 + kq);
    #pragma unroll
    for (int i = 0; i < 4; ++i) bf[i] = *(const short8*)(Bs + (wn + i * 16 + cl) * 40 + kq);
    #pragma unroll
    for (int mi = 0; mi < 4; ++mi)
      #pragma unroll
      for (int ni = 0; ni < 4; ++ni)
        acc[mi][ni] = __builtin_amdgcn_mfma_f32_16x16x32_bf16(af[mi], bf[ni], acc[mi][ni], 0, 0, 0);
    __syncthreads();
  }
  #pragma unroll
  for (int ni = 0; ni < 4; ++ni){
    const int c = n0 + wn + ni * 16 + cl;
    const float bsv = bias ? bias[c] : 0.f;
    #pragma unroll
    for (int mi = 0; mi < 4; ++mi){
      const int m = m0 + wm + mi * 16 + bg * 4;
      const float v0 = acc[mi][ni].x + bsv, v1 = acc[mi][ni].y + bsv;
      const float v2 = acc[mi][ni].z + bsv, v3 = acc[mi][ni].w + bsv;
      if (OUT_BF16){
        Cb[(size_t)(m + 0) * Nn + c] = f2bf(v0);
        Cb[(size_t)(m + 1) * Nn + c] = f2bf(v1);
        Cb[(size_t)(m + 2) * Nn + c] = f2bf(v2);
        Cb[(size_t)(m + 3) * Nn + c] = f2bf(v3);
      } else {
        Cf[(size_t)(m + 0) * Nn + c] = v0;
        Cf[(size_t)(m + 1) * Nn + c] = v1;
        Cf[(size_t)(m + 2) * Nn + c] = v2;
        Cf[(size_t)(m + 3) * Nn + c] = v3;
      }
    }
  }
}

// ---------------- span attention: one block per (b, head) ----------------
__global__ __launch_bounds__(256) void k_attn(const unsigned short* __restrict__ qb,
    const unsigned short* __restrict__ kb, const unsigned short* __restrict__ vb,
    const int* __restrict__ mask, unsigned short* __restrict__ ctx){
  const int bh = blockIdx.x, b = bh >> 4, hd = bh & 15;
  __shared__ float Q[32][64], K[32][64], V[32][64], Sc[32][33];
  __shared__ int msk[32];
  const int tid = threadIdx.x;
  const int row = tid >> 3, d0 = (tid & 7) * 8;
  {
    const size_t base = (size_t)(b * NS_ + row) * H_ + hd * 64 + d0;
    uint4 vq = *(const uint4*)(qb + base);
    uint4 vk = *(const uint4*)(kb + base);
    uint4 vv = *(const uint4*)(vb + base);
    const unsigned int wq[4] = {vq.x, vq.y, vq.z, vq.w};
    const unsigned int wk[4] = {vk.x, vk.y, vk.z, vk.w};
    const unsigned int wv[4] = {vv.x, vv.y, vv.z, vv.w};
    #pragma unroll
    for (int i = 0; i < 4; ++i){
      Q[row][d0 + 2*i]     = bf2f((unsigned short)(wq[i] & 0xffff));
      Q[row][d0 + 2*i + 1] = bf2f((unsigned short)(wq[i] >> 16));
      K[row][d0 + 2*i]     = bf2f((unsigned short)(wk[i] & 0xffff));
      K[row][d0 + 2*i + 1] = bf2f((unsigned short)(wk[i] >> 16));
      V[row][d0 + 2*i]     = bf2f((unsigned short)(wv[i] & 0xffff));
      V[row][d0 + 2*i + 1] = bf2f((unsigned short)(wv[i] >> 16));
    }
  }
  if (tid < 32) msk[tid] = mask[b * NS_ + tid];
  __syncthreads();
  {
    const int qi = tid >> 3, kb0 = (tid & 7) * 4;
    for (int kk = kb0; kk < kb0 + 4; ++kk){
      float s = 0.f;
      #pragma unroll
      for (int d = 0; d < 64; ++d) s += Q[qi][d] * K[kk][d];
      s *= 0.125f;
      if (!msk[qi] || !msk[kk]) s = -3.402823466e38f;
      Sc[qi][kk] = s;
    }
  }
  __syncthreads();
  if (tid < 32){
    float mx = -3.402823466e38f;
    for (int kk = 0; kk < 32; ++kk) mx = fmaxf(mx, Sc[tid][kk]);
    float sum = 0.f;
    for (int kk = 0; kk < 32; ++kk){
      const float e = __expf(Sc[tid][kk] - mx);
      Sc[tid][kk] = e; sum += e;
    }
    const float isum = 1.f / sum;
    for (int kk = 0; kk < 32; ++kk){
      float pv = Sc[tid][kk] * isum;
      if (!msk[tid] || !msk[kk]) pv = 0.f;
      Sc[tid][kk] = pv;
    }
  }
  __syncthreads();
  float o[8] = {0,0,0,0,0,0,0,0};
  for (int kk = 0; kk < 32; ++kk){
    const float p = Sc[row][kk];
    #pragma unroll
    for (int i = 0; i < 8; ++i) o[i] += p * V[kk][d0 + i];
  }
  ushort4 oA, oB;
  oA.x = f2bf(o[0]); oA.y = f2bf(o[1]); oA.z = f2bf(o[2]); oA.w = f2bf(o[3]);
  oB.x = f2bf(o[4]); oB.y = f2bf(o[5]); oB.z = f2bf(o[6]); oB.w = f2bf(o[7]);
  unsigned short* cp = ctx + (size_t)(b * NS_ + row) * H_ + hd * 64 + d0;
  *(ushort4*)(cp) = oA;
  *(ushort4*)(cp + 4) = oB;
}

// ---------------- residual + LayerNorm -> attn_out (f32) ----------------
__global__ __launch_bounds__(256) void k_residln(const float* __restrict__ wo,
    const float* __restrict__ mvf, const float* __restrict__ gamma,
    const float* __restrict__ beta, float* __restrict__ aof){
  __shared__ float red[4];
  const int m = blockIdx.x, tid = threadIdx.x;
  float4 a = *(const float4*)(wo + (size_t)m * H_ + tid * 4);
  float4 r = *(const float4*)(mvf + (size_t)m * H_ + tid * 4);
  float4 x; x.x = a.x + r.x; x.y = a.y + r.y; x.z = a.z + r.z; x.w = a.w + r.w;
  const float mu = block_sum(x.x + x.y + x.z + x.w, red, tid) * (1.f / (float)H_);
  const float d0 = x.x - mu, d1 = x.y - mu, d2 = x.z - mu, d3 = x.w - mu;
  const float var = block_sum(d0*d0 + d1*d1 + d2*d2 + d3*d3, red, tid) * (1.f / (float)H_);
  const float rs = rsqrtf(var + 1e-7f);
  float4 gm = *(const float4*)(gamma + tid * 4);
  float4 bt = *(const float4*)(beta + tid * 4);
  float4 o; o.x = d0*rs*gm.x + bt.x; o.y = d1*rs*gm.y + bt.y;
  o.z = d2*rs*gm.z + bt.z; o.w = d3*rs*gm.w + bt.w;
  *(float4*)(aof + (size_t)m * H_ + tid * 4) = o;
}

// ---------------- classifier: logits[m][l] ----------------
__global__ __launch_bounds__(64) void k_clf(const float* __restrict__ ao,
    const float* __restrict__ Wc, const float* __restrict__ bc, float* __restrict__ out){
  const int m = blockIdx.x, l = threadIdx.x;
  const float* a = ao + (size_t)m * H_ + l * 16;
  float av[16];
  #pragma unroll
  for (int i = 0; i < 4; ++i){
    float4 v = *(const float4*)(a + i * 4);
    av[i*4+0] = v.x; av[i*4+1] = v.y; av[i*4+2] = v.z; av[i*4+3] = v.w;
  }
  float p[5];
  #pragma unroll
  for (int c = 0; c < 5; ++c){
    const float* wr = Wc + (size_t)c * H_ + l * 16;
    float s = 0.f;
    #pragma unroll
    for (int i = 0; i < 4; ++i){
      float4 v = *(const float4*)(wr + i * 4);
      s += av[i*4+0]*v.x + av[i*4+1]*v.y + av[i*4+2]*v.z + av[i*4+3]*v.w;
    }
    p[c] = s;
  }
  #pragma unroll
  for (int d = 1; d < 64; d <<= 1){
    #pragma unroll
    for (int c = 0; c < 5; ++c) p[c] += __shfl_xor(p[c], d, 64);
  }
  if (l == 0){
    #pragma unroll
    for (int c = 0; c < 5; ++c) out[m * L_ + c] = p[c] + bc[c];
  }
}

extern "C" void kernel_launch(void* const* d_in, const int* in_sizes, int n_in,
                              void* d_out, int out_size, void* d_ws, size_t ws_size,
                              hipStream_t stream){
  (void)in_sizes; (void)n_in; (void)out_size; (void)ws_size;
  const float* enc  = (const float*)d_in[0];
  const float* Wih  = (const float*)d_in[1];
  const float* Whh  = (const float*)d_in[2];
  const float* bih  = (const float*)d_in[3];
  const float* bhh  = (const float*)d_in[4];
  const float* lng  = (const float*)d_in[5];
  const float* lnb  = (const float*)d_in[6];
  const float* Wq   = (const float*)d_in[7];
  const float* bq   = (const float*)d_in[8];
  const float* Wk   = (const float*)d_in[9];
  const float* bk   = (const float*)d_in[10];
  const float* Wv   = (const float*)d_in[11];
  const float* bv   = (const float*)d_in[12];
  const float* Wo   = (const float*)d_in[13];
  const float* bo   = (const float*)d_in[14];
  const float* alng = (const float*)d_in[15];
  const float* alnb = (const float*)d_in[16];
  const float* clfW = (const float*)d_in[17];
  const float* clfb = (const float*)d_in[18];
  const int* shead  = (const int*)d_in[19];
  const int* stail  = (const int*)d_in[20];
  const int* smask  = (const int*)d_in[21];
  float* out = (float*)d_out;
  unsigned char* ws = (unsigned char*)d_ws;

  size_t cur = 0;
  auto alloc = [&](size_t sz){ size_t r = cur; cur = (cur + sz + 255) & ~(size_t)255; return r; };
  const size_t off_gx   = alloc((size_t)S_ * G4H * B_ * 2);     // 134 MB bf16, per-block layout
  const size_t off_hbuf = alloc(2 * (size_t)B_ * H_ * 2);       // 64 KB, 2 parities, swizzled image
  const size_t off_tags = alloc(2 * 1024 * 4);                  // 8 KB tag flags (64B stride)
  const size_t off_span = alloc((size_t)B_ * S_ * 4);
  const size_t off_sums = alloc((size_t)B_ * NS_ * H_ * 4);
  const size_t off_mvb  = alloc((size_t)B_ * NS_ * H_ * 2);
  const size_t off_mvf  = alloc((size_t)B_ * NS_ * H_ * 4);
  const size_t off_q    = alloc((size_t)B_ * NS_ * H_ * 2);
  const size_t off_k    = alloc((size_t)B_ * NS_ * H_ * 2);
  const size_t off_v    = alloc((size_t)B_ * NS_ * H_ * 2);
  const size_t off_ctx  = alloc((size_t)B_ * NS_ * H_ * 2);
  const size_t off_wo   = alloc((size_t)B_ * NS_ * H_ * 4);
  const size_t off_ao   = alloc((size_t)B_ * NS_ * H_ * 4);

  unsigned short* gx   = (unsigned short*)(ws + off_gx);
  unsigned short* hbuf = (unsigned short*)(ws + off_hbuf);
  unsigned int*   tags = (unsigned int*)(ws + off_tags);
  int*            span = (int*)(ws + off_span);
  float*          sums = (float*)(ws + off_sums);
  unsigned short* mvb  = (unsigned short*)(ws + off_mvb);
  float*          mvf  = (float*)(ws + off_mvf);
  unsigned short* qb   = (unsigned short*)(ws + off_q);
  unsigned short* kbp  = (unsigned short*)(ws + off_k);
  unsigned short* vbp  = (unsigned short*)(ws + off_v);
  unsigned short* ctx  = (unsigned short*)(ws + off_ctx);
  float*          wob  = (float*)(ws + off_wo);
  float*          aof  = (float*)(ws + off_ao);

  (void)hipMemsetAsync(hbuf, 0, 2 * (size_t)B_ * H_ * 2, stream);
  (void)hipMemsetAsync(tags, 0, 2 * 1024 * 4, stream);
  (void)hipMemsetAsync(sums, 0, (size_t)B_ * NS_ * H_ * 4, stream);

  k_spanof<<<B_, 256, 0, stream>>>(shead, stail, span);
  k_gates<<<dim3(32, 128), 256, 0, stream>>>(enc, Wih, bih, bhh, gx);

  k_lstm<<<LSTM_GRID, 256, 0, stream>>>(Whh, gx, span, hbuf, tags, sums);

  k_poolln<<<B_ * NS_, 256, 0, stream>>>(sums, shead, stail, lng, lnb, mvb, mvf);
  k_gemm2<1><<<dim3(8, 4), 256, 0, stream>>>(mvb, Wq, bq, nullptr, qb, 1024);
  k_gemm2<1><<<dim3(8, 4), 256, 0, stream>>>(mvb, Wk, bk, nullptr, kbp, 1024);
  k_gemm2<1><<<dim3(8, 4), 256, 0, stream>>>(mvb, Wv, bv, nullptr, vbp, 1024);
  k_attn<<<B_ * HEADS_, 256, 0, stream>>>(qb, kbp, vbp, smask, ctx);
  k_gemm2<0><<<dim3(8, 4), 256, 0, stream>>>(ctx, Wo, bo, wob, nullptr, 1024);
  k_residln<<<B_ * NS_, 256, 0, stream>>>(wob, mvf, alng, alnb, aof);
  k_clf<<<B_ * NS_, 64, 0, stream>>>(aof, clfW, clfb, out);
}